// Round 1
// baseline (429.689 us; speedup 1.0000x reference)
//
#include <hip/hip_runtime.h>

// Problem constants: H=8, B=16, G=512, NQ=512, D=512, KD=VD=64, E=512, NORM=0.125
using u8 = unsigned char;
using u16 = unsigned short;
using u32 = unsigned int;
using u64 = unsigned long long;

typedef __attribute__((ext_vector_type(8))) __bf16 bf16x8;
typedef __attribute__((ext_vector_type(8))) u16 u16x8;
typedef __attribute__((ext_vector_type(4))) float f32x4;

#define MFMA16(A, B, C) __builtin_amdgcn_mfma_f32_16x16x32_bf16((A), (B), (C), 0, 0, 0)

__device__ __forceinline__ u16 f2bf(float f) {
  u32 u = __builtin_bit_cast(u32, f);
  u += 0x7fffu + ((u >> 16) & 1u);   // round-to-nearest-even
  return (u16)(u >> 16);
}

// async 16B/lane global->LDS DMA. lds dest must be wave-uniform base; lane i
// lands at base + i*16.
__device__ __forceinline__ void gl_lds16(const void* g, void* l) {
  __builtin_amdgcn_global_load_lds(
      (const __attribute__((address_space(1))) void*)g,
      (__attribute__((address_space(3))) void*)l, 16, 0, 0);
}

// ---------------------------------------------------------------- prep kernels

__global__ void prep_q_k(const float* __restrict__ q, u16* __restrict__ qb) {
  int idx = blockIdx.x * 256 + threadIdx.x;          // one per 8 elems
  const float4* p = (const float4*)q + (size_t)idx * 2;
  float4 a = p[0], b = p[1];
  u32 w0 = f2bf(a.x) | ((u32)f2bf(a.y) << 16);
  u32 w1 = f2bf(a.z) | ((u32)f2bf(a.w) << 16);
  u32 w2 = f2bf(b.x) | ((u32)f2bf(b.y) << 16);
  u32 w3 = f2bf(b.z) | ((u32)f2bf(b.w) << 16);
  ((uint4*)qb)[idx] = make_uint4(w0, w1, w2, w3);
}

struct WPtrs { const float* w[12]; };

// Wbt[col][d] = W_iw[h][d][kk],  col = iw*512 + h*64 + kk  (K-major for B-fragments)
// Q-branch weights (iw%3==0) pre-scaled by 0.125*log2(e) so attn uses bare exp2.
__global__ void prep_w_k(WPtrs wp, u16* __restrict__ Wbt) {
  int iw = blockIdx.x >> 3;
  int h  = blockIdx.x & 7;
  int kk = threadIdx.x & 63;
  int dd = threadIdx.x >> 6;
  float scale = ((iw % 3) == 0) ? 0.18033688011112042f : 1.0f;  // 0.125*log2e
  const float* W = wp.w[iw];
  for (int d = dd; d < 512; d += 4) {
    float v = W[((size_t)(h * 512 + d)) * 64 + kk] * scale;   // coalesced over kk
    Wbt[((size_t)(iw * 512 + h * 64 + kk)) * 512 + d] = f2bf(v);
  }
}

// Wot[h][e][v] = W_out[h][v][e]
__global__ void prep_wout_k(const float* __restrict__ wout, u16* __restrict__ Wot) {
  int h = blockIdx.x;
  int t = threadIdx.x;
  for (int ee = 0; ee < 2; ee++) {
    int e = ee * 256 + t;
    for (int v = 0; v < 64; v++)
      Wot[((size_t)(h * 512 + e)) * 64 + v] = f2bf(wout[((size_t)(h * 64 + v)) * 512 + e]);
  }
}

// ---------------------------------------------------------------- mask bit-pack
// RB[b][c][q][gc] (u64): bit (g&63) of chunk gc = mask_c(b, q, gc*64+g)
//   c0 = sd[b][q][g], c1 = att[b][g][q], c2 = att_flat[b][q][g], c3 = grp[b][q][g]

__global__ void pack_rows_k(const int* __restrict__ att, const int* __restrict__ grp,
                            const int* __restrict__ sd, u64* __restrict__ RB) {
  int t = threadIdx.x, wave = t >> 6, lane = t & 63;
  int b = blockIdx.x >> 5, qc = blockIdx.x & 31;   // 512 blocks
  int q0 = qc * 16 + wave * 4;
#pragma unroll
  for (int r = 0; r < 4; r++) {
    int q = q0 + r;
    size_t rbase = ((size_t)(b * 512 + q)) * 512;
#pragma unroll
    for (int gc = 0; gc < 8; gc++) {
      u64 m0 = __ballot(sd [rbase + gc * 64 + lane] != 0);
      u64 m2 = __ballot(att[rbase + gc * 64 + lane] != 0);
      u64 m3 = __ballot(grp[rbase + gc * 64 + lane] != 0);
      if (lane == 0) {
        size_t ob = ((size_t)(b * 4) * 512 + q) * 8 + gc;
        RB[ob]            = m0;   // c0
        RB[ob + 2 * 4096] = m2;   // c2
        RB[ob + 3 * 4096] = m3;   // c3
      }
    }
  }
}

__global__ void pack_cols_k(const int* __restrict__ att, u64* __restrict__ RB) {
  int t = threadIdx.x, wave = t >> 6, lane = t & 63;
  int b = blockIdx.x >> 3, gc = blockIdx.x & 7;    // 128 blocks
  const int* col = att + ((size_t)(b * 512 + gc * 64 + lane)) * 512;  // att[b][g][.]
#pragma unroll 4
  for (int qi = 0; qi < 128; qi++) {
    int q = wave * 128 + qi;
    u64 m = __ballot(col[q] != 0);
    if (lane == 0) RB[((size_t)(b * 4 + 1) * 512 + q) * 8 + gc] = m;
  }
}

// ---------------------------------------------------------------- pass A: all 12 projections
// C(8192 x 6144) = qb(8192 x 512) * W(512 x 6144). 128x128 tile, BK=64, 4 waves.
__global__ __launch_bounds__(256) void gemm_proj_k(const u16* __restrict__ qb,
                                                   const u16* __restrict__ Wbt,
                                                   u16* __restrict__ P) {
  __shared__ __align__(16) u16 smem[17408];  // As 8192 | Bs 8192; Cs overlays 128x136
  u16* As = smem;
  u16* Bs = smem + 8192;
  int t = threadIdx.x;
  int wave = t >> 6, lane = t & 63, quad = lane >> 4, l16 = lane & 15;
  int m0w = (wave >> 1) * 64, n0w = (wave & 1) * 64;
  int bm = blockIdx.x, bn = blockIdx.y;
  f32x4 acc[4][4] = {};
  int lr8 = lane >> 3;                 // 0..7
  int lc8 = (lane & 7) ^ lr8;         // swizzled logical chunk to fetch
  const u16* ag = qb  + ((size_t)(bm * 128 + wave * 32 + lr8)) * 512 + lc8 * 8;
  const u16* bg = Wbt + ((size_t)(bn * 128 + wave * 32 + lr8)) * 512 + lc8 * 8;
  u16* Asd = As + wave * 2048;        // wave*4 issues * 512 u16
  u16* Bsd = Bs + wave * 2048;
  for (int k0 = 0; k0 < 512; k0 += 64) {
    __syncthreads();                  // prev tile's LDS reads done
#pragma unroll
    for (int j = 0; j < 4; j++) {
      gl_lds16(ag + (size_t)j * 8 * 512 + k0, Asd + j * 512);
      gl_lds16(bg + (size_t)j * 8 * 512 + k0, Bsd + j * 512);
    }
    __syncthreads();                  // vmcnt(0) drain: tiles resident
#pragma unroll
    for (int kc = 0; kc < 2; kc++) {
      bf16x8 am[4], bnf[4];
#pragma unroll
      for (int i = 0; i < 4; i++) {
        int ca = ((kc * 4 + quad) ^ (l16 & 7)) * 8;
        am[i]  = *(const bf16x8*)&As[(m0w + i * 16 + l16) * 64 + ca];
        bnf[i] = *(const bf16x8*)&Bs[(n0w + i * 16 + l16) * 64 + ca];
      }
#pragma unroll
      for (int mt = 0; mt < 4; mt++)
#pragma unroll
        for (int nt = 0; nt < 4; nt++)
          acc[mt][nt] = MFMA16(am[mt], bnf[nt], acc[mt][nt]);
    }
  }
  // ---------------- epilogue: LDS-staged coalesced stores ----------------
  int iw = bn >> 2;                  // both 64-col groups share iw
  bool isV = (iw % 3) == 2;
  int b  = bm >> 2;
  int n0 = (bm & 3) * 128;
  u16 (*Cs)[136] = (u16(*)[136])smem;  // 128 x 136 u16 = 34816 B
  __syncthreads();
#pragma unroll
  for (int mt = 0; mt < 4; mt++)
#pragma unroll
    for (int nt = 0; nt < 4; nt++)
#pragma unroll
      for (int r = 0; r < 4; r++) {
        int rm = m0w + mt * 16 + quad * 4 + r;
        int cn = n0w + nt * 16 + l16;
        u16 v = f2bf(acc[mt][nt][r]);
        if (!isV) Cs[rm][cn] = v;
        else      Cs[cn][rm] = v;
      }
  __syncthreads();
#pragma unroll
  for (int p = 0; p < 8; p++) {
    int idx = p * 256 + t;
    int seg  = idx & 15;
    int crow = idx >> 4;
    uint4 v = *(const uint4*)&Cs[crow][seg * 8];
    if (!isV) {
      int col = seg * 8;
      int cg = col >> 6, k = col & 63;
      int h = (bn * 2 + cg) & 7;
      u16* dst = P + ((size_t)((iw * 8 + h) * 16 + b)) * 32768 + (size_t)(n0 + crow) * 64 + k;
      *(uint4*)dst = v;
    } else {
      int cg = crow >> 6, k = crow & 63;
      int h = (bn * 2 + cg) & 7;
      u16* dst = P + ((size_t)((iw * 8 + h) * 16 + b)) * 32768 + (size_t)k * 512 + n0 + seg * 8;
      *(uint4*)dst = v;
    }
  }
}

// ---------------------------------------------------------------- pass B: fused masked attention
// grid (qt=8, b=16, h=8); block 256 = 4 waves, each wave owns 16 q-rows.
// Single-barrier-per-gt pipeline: K/V double-buffered in LDS; next tile's DMA
// issued BEFORE compute so it overlaps the MFMA/softmax phase (drained by the
// compiler's vmcnt(0) at the next barrier). Masks: row-packed u64 bits, staged
// once per class (4KB). Denominator: extra MFMA with ones-B operand (no VALU
// adds, no epilogue shuffles). Q-weights pre-scaled -> bare exp2f.
__global__ __launch_bounds__(256) void attn_k(const u16* __restrict__ P,
                                              const u64* __restrict__ RB,
                                              u16* __restrict__ heads) {
  __shared__ __align__(16) u16 Qs[4096];     // [64][64] swizzled
  __shared__ __align__(16) u16 Ks[8192];     // 2 x [64][64] double-buffer
  __shared__ __align__(16) u16 Vs[8192];     // 2 x [64][64] (transposed [v][g])
  __shared__ __align__(16) u16 Ps[4096];     // [64][64] chunk-XOR-swizzled
  __shared__ __align__(16) u64 Ms[64][8];    // per-class row bitmasks
  int t = threadIdx.x;
  int wave = t >> 6, lane = t & 63, quad = lane >> 4, l16 = lane & 15;
  int qt = blockIdx.x, b = blockIdx.y, h = blockIdx.z;
  int q0 = qt * 64;
  int lr8 = lane >> 3, lc8 = (lane & 7) ^ lr8;
  int shA = 31 - l16, shB = 15 - l16;
  f32x4 O[4] = {};
  f32x4 Oden = {};
  u16x8 ov = {0x3F80, 0x3F80, 0x3F80, 0x3F80, 0x3F80, 0x3F80, 0x3F80, 0x3F80};
  bf16x8 ones = __builtin_bit_cast(bf16x8, ov);   // bf16 1.0 x8

  auto issueKV = [&](int c, int g0, int buf) {
    const u16* PK = P + ((size_t)((3 * c + 1) * 8 + h) * 16 + b) * 32768;
    const u16* PV = P + ((size_t)((3 * c + 2) * 8 + h) * 16 + b) * 32768;
    u16* Kd = Ks + buf * 4096 + wave * 1024;
    u16* Vd = Vs + buf * 4096 + wave * 1024;
#pragma unroll
    for (int j = 0; j < 2; j++) {
      gl_lds16(PK + (size_t)(g0 + wave * 16 + j * 8 + lr8) * 64 + lc8 * 8, Kd + j * 512);
      gl_lds16(PV + (size_t)(wave * 16 + j * 8 + lr8) * 512 + g0 + lc8 * 8, Vd + j * 512);
    }
  };
  auto issueQM = [&](int c) {
    const u16* PQ = P + ((size_t)((3 * c) * 8 + h) * 16 + b) * 32768;
#pragma unroll
    for (int j = 0; j < 2; j++)
      gl_lds16(PQ + (size_t)(q0 + wave * 16 + j * 8 + lr8) * 64 + lc8 * 8,
               Qs + wave * 1024 + j * 512);
    // 1KB/wave of row bitmasks: rows q0+wave*16..+15, all 8 g-chunks
    gl_lds16((const char*)RB + ((size_t)((b * 4 + c) * 512 + q0 + wave * 16)) * 64 + lane * 16,
             &Ms[wave * 16][0]);
  };

  issueQM(0);
  issueKV(0, 0, 0);
  int cur = 0;
  bf16x8 aq0, aq1;
  for (int c = 0; c < 4; c++) {
    for (int gt = 0; gt < 8; gt++) {
      __syncthreads();               // buf[cur] (+Qs/Ms at gt==0) resident
      if (gt == 0) {                 // Q fragments are gt-invariant: hoist
        aq0 = *(const bf16x8*)&Qs[(wave * 16 + l16) * 64 + ((quad) ^ (l16 & 7)) * 8];
        aq1 = *(const bf16x8*)&Qs[(wave * 16 + l16) * 64 + ((4 + quad) ^ (l16 & 7)) * 8];
      }
      if (gt < 7) issueKV(c, (gt + 1) * 64, cur ^ 1);   // overlaps compute below
      const u16* Kc = Ks + cur * 4096;
      const u16* Vc = Vs + cur * 4096;
      f32x4 S[4];
#pragma unroll
      for (int nt = 0; nt < 4; nt++) {
        bf16x8 bk0 = *(const bf16x8*)&Kc[(nt * 16 + l16) * 64 + ((quad) ^ (l16 & 7)) * 8];
        bf16x8 bk1 = *(const bf16x8*)&Kc[(nt * 16 + l16) * 64 + ((4 + quad) ^ (l16 & 7)) * 8];
        f32x4 sa = {};
        sa = MFMA16(aq0, bk0, sa);
        sa = MFMA16(aq1, bk1, sa);
        S[nt] = sa;
      }
#pragma unroll
      for (int r = 0; r < 4; r++) {
        u64 m = Ms[wave * 16 + quad * 4 + r][gt];       // broadcast b64, conflict-free
        u32 mlo = (u32)m, mhi = (u32)(m >> 32);
        int prow = wave * 16 + quad * 4 + r;
        int rx = prow & 7;
#pragma unroll
        for (int nt = 0; nt < 4; nt++) {
          float e = exp2f(S[nt][r]);                    // W_Q pre-scaled by 0.125*log2e
          u32 w2 = (nt & 2) ? mhi : mlo;
          int sh = (nt & 1) ? shB : shA;
          u32 msk = (u32)((int)(w2 << sh) >> 31);       // bit -> all-ones/zero
          u32 em = __builtin_bit_cast(u32, e) & msk;
          int pcol = (((nt * 2 + (l16 >> 3)) ^ rx) * 8) + (l16 & 7);
          Ps[prow * 64 + pcol] = (u16)((em + 0x8000u) >> 16);
        }
      }
#pragma unroll
      for (int kc = 0; kc < 2; kc++) {
        bf16x8 ap = *(const bf16x8*)&Ps[(wave * 16 + l16) * 64 + (((kc * 4 + quad) ^ (l16 & 7)) * 8)];
#pragma unroll
        for (int vt = 0; vt < 4; vt++) {
          bf16x8 bv = *(const bf16x8*)&Vc[(vt * 16 + l16) * 64 + (((kc * 4 + quad) ^ (l16 & 7)) * 8)];
          O[vt] = MFMA16(ap, bv, O[vt]);
        }
        Oden = MFMA16(ap, ones, Oden);                  // row-sum of P = denominator
      }
      cur ^= 1;
    }
    if (c < 3) {
      __syncthreads();               // all reads of Qs/Ms/buffers done
      issueQM(c + 1);
      issueKV(c + 1, 0, cur);
    }
  }
#pragma unroll
  for (int r = 0; r < 4; r++) {
    float den = Oden[r];             // every lane holds its rows' denominator
#pragma unroll
    for (int vt = 0; vt < 4; vt++) {
      float val = (den > 0.f) ? O[vt][r] / den : 0.f;
      heads[((size_t)(h * 16 + b) * 512 + q0 + wave * 16 + quad * 4 + r) * 64 + vt * 16 + l16] =
          f2bf(val);
    }
  }
}

// ---------------------------------------------------------------- pass C: out = heads x W_out
// out(8192 x 512) = heads[(b,q),(h,v)=512] * Wot. 64x64 tile, K-loop over h.
__global__ __launch_bounds__(256) void gemm_out_k(const u16* __restrict__ heads,
                                                  const u16* __restrict__ Wot,
                                                  float* __restrict__ out) {
  __shared__ __align__(16) u16 As[4096];
  __shared__ __align__(16) u16 Bs[4096];
  int t = threadIdx.x;
  int wave = t >> 6, lane = t & 63, quad = lane >> 4, l16 = lane & 15;
  int m0 = blockIdx.x * 64, e0 = blockIdx.y * 64;
  int b = m0 >> 9, q0 = m0 & 511;
  int lr8 = lane >> 3, lc8 = (lane & 7) ^ lr8;
  f32x4 acc[4] = {};
  for (int h = 0; h < 8; h++) {
    __syncthreads();
#pragma unroll
    for (int j = 0; j < 2; j++) {
      gl_lds16(heads + ((size_t)(h * 16 + b) * 512 + q0 + wave * 16 + j * 8 + lr8) * 64 + lc8 * 8,
               As + wave * 1024 + j * 512);
      gl_lds16(Wot + ((size_t)(h * 512 + e0 + wave * 16 + j * 8 + lr8)) * 64 + lc8 * 8,
               Bs + wave * 1024 + j * 512);
    }
    __syncthreads();
#pragma unroll
    for (int kc = 0; kc < 2; kc++) {
      bf16x8 af = *(const bf16x8*)&As[(wave * 16 + l16) * 64 + ((kc * 4 + quad) ^ (l16 & 7)) * 8];
#pragma unroll
      for (int nt = 0; nt < 4; nt++) {
        bf16x8 bfr = *(const bf16x8*)&Bs[(nt * 16 + l16) * 64 + ((kc * 4 + quad) ^ (l16 & 7)) * 8];
        acc[nt] = MFMA16(af, bfr, acc[nt]);
      }
    }
  }
#pragma unroll
  for (int nt = 0; nt < 4; nt++)
#pragma unroll
    for (int r = 0; r < 4; r++)
      out[((size_t)(b * 512 + q0 + wave * 16 + quad * 4 + r)) * 512 + e0 + nt * 16 + l16] = acc[nt][r];
}

// ---------------------------------------------------------------- launch

extern "C" void kernel_launch(void* const* d_in, const int* in_sizes, int n_in,
                              void* d_out, int out_size, void* d_ws, size_t ws_size,
                              hipStream_t stream) {
  const float* q   = (const float*)d_in[0];
  const int*   att = (const int*)d_in[1];
  const int*   grp = (const int*)d_in[2];
  const int*   sd  = (const int*)d_in[3];
  WPtrs wp;
  for (int j = 0; j < 12; j++) wp.w[j] = (const float*)d_in[4 + j];
  const float* wout = (const float*)d_in[16];

  char* ws = (char*)d_ws;
  // workspace layout (total 126,353,408 B)
  u16* qb    = (u16*)(ws + 0);            //   8,388,608
  u16* Wbt   = (u16*)(ws + 8388608);      //   6,291,456
  u16* Wot   = (u16*)(ws + 14680064);     //     524,288
  u64* RB    = (u64*)(ws + 15204352);     //   2,097,152  (bit-packed masks)
  u16* P     = (u16*)(ws + 17301504);     // 100,663,296
  u16* heads = (u16*)(ws + 117964800);    //   8,388,608
  float* out = (float*)d_out;

  pack_rows_k<<<512, 256, 0, stream>>>(att, grp, sd, RB);
  pack_cols_k<<<128, 256, 0, stream>>>(att, RB);
  prep_q_k<<<2048, 256, 0, stream>>>(q, qb);
  prep_w_k<<<96, 256, 0, stream>>>(wp, Wbt);
  prep_wout_k<<<8, 256, 0, stream>>>(wout, Wot);
  gemm_proj_k<<<dim3(64, 48), 256, 0, stream>>>(qb, Wbt, P);
  attn_k<<<dim3(8, 16, 8), 256, 0, stream>>>(P, RB, heads);
  gemm_out_k<<<dim3(128, 8), 256, 0, stream>>>(heads, Wot, out);
}

// Round 2
// 414.773 us; speedup vs baseline: 1.0360x; 1.0360x over previous
//
#include <hip/hip_runtime.h>

// Problem constants: H=8, B=16, G=512, NQ=512, D=512, KD=VD=64, E=512, NORM=0.125
using u8 = unsigned char;
using u16 = unsigned short;
using u32 = unsigned int;
using u64 = unsigned long long;

typedef __attribute__((ext_vector_type(8))) __bf16 bf16x8;
typedef __attribute__((ext_vector_type(8))) u16 u16x8;
typedef __attribute__((ext_vector_type(4))) float f32x4;

#define MFMA16(A, B, C) __builtin_amdgcn_mfma_f32_16x16x32_bf16((A), (B), (C), 0, 0, 0)

__device__ __forceinline__ u16 f2bf(float f) {
  u32 u = __builtin_bit_cast(u32, f);
  u += 0x7fffu + ((u >> 16) & 1u);   // round-to-nearest-even
  return (u16)(u >> 16);
}

// async 16B/lane global->LDS DMA. lds dest must be wave-uniform base; lane i
// lands at base + i*16.
__device__ __forceinline__ void gl_lds16(const void* g, void* l) {
  __builtin_amdgcn_global_load_lds(
      (const __attribute__((address_space(1))) void*)g,
      (__attribute__((address_space(3))) void*)l, 16, 0, 0);
}

// ---------------------------------------------------------------- prep kernels

__global__ void prep_q_k(const float* __restrict__ q, u16* __restrict__ qb) {
  int idx = blockIdx.x * 256 + threadIdx.x;          // one per 8 elems
  const float4* p = (const float4*)q + (size_t)idx * 2;
  float4 a = p[0], b = p[1];
  u32 w0 = f2bf(a.x) | ((u32)f2bf(a.y) << 16);
  u32 w1 = f2bf(a.z) | ((u32)f2bf(a.w) << 16);
  u32 w2 = f2bf(b.x) | ((u32)f2bf(b.y) << 16);
  u32 w3 = f2bf(b.z) | ((u32)f2bf(b.w) << 16);
  ((uint4*)qb)[idx] = make_uint4(w0, w1, w2, w3);
}

struct WPtrs { const float* w[12]; };

// Wbt[col][d] = W_iw[h][d][kk],  col = iw*512 + h*64 + kk  (K-major for B-fragments)
// Q-branch weights (iw%3==0) pre-scaled by 0.125*log2(e) so attn uses bare exp2.
__global__ void prep_w_k(WPtrs wp, u16* __restrict__ Wbt) {
  int iw = blockIdx.x >> 3;
  int h  = blockIdx.x & 7;
  int kk = threadIdx.x & 63;
  int dd = threadIdx.x >> 6;
  float scale = ((iw % 3) == 0) ? 0.18033688011112042f : 1.0f;  // 0.125*log2e
  const float* W = wp.w[iw];
  for (int d = dd; d < 512; d += 4) {
    float v = W[((size_t)(h * 512 + d)) * 64 + kk] * scale;   // coalesced over kk
    Wbt[((size_t)(iw * 512 + h * 64 + kk)) * 512 + d] = f2bf(v);
  }
}

// Wot[h][e][v] = W_out[h][v][e]
__global__ void prep_wout_k(const float* __restrict__ wout, u16* __restrict__ Wot) {
  int h = blockIdx.x;
  int t = threadIdx.x;
  for (int ee = 0; ee < 2; ee++) {
    int e = ee * 256 + t;
    for (int v = 0; v < 64; v++)
      Wot[((size_t)(h * 512 + e)) * 64 + v] = f2bf(wout[((size_t)(h * 64 + v)) * 512 + e]);
  }
}

// ---------------------------------------------------------------- mask bit-pack
// RB[b][c][q][gc] (u64): bit (g&63) of chunk gc = mask_c(b, q, gc*64+g)
//   c0 = sd[b][q][g], c1 = att[b][g][q], c2 = att_flat[b][q][g], c3 = grp[b][q][g]

__global__ void pack_rows_k(const int* __restrict__ att, const int* __restrict__ grp,
                            const int* __restrict__ sd, u64* __restrict__ RB) {
  int t = threadIdx.x, wave = t >> 6, lane = t & 63;
  int b = blockIdx.x >> 5, qc = blockIdx.x & 31;   // 512 blocks
  int q0 = qc * 16 + wave * 4;
#pragma unroll
  for (int r = 0; r < 4; r++) {
    int q = q0 + r;
    size_t rbase = ((size_t)(b * 512 + q)) * 512;
#pragma unroll
    for (int gc = 0; gc < 8; gc++) {
      u64 m0 = __ballot(sd [rbase + gc * 64 + lane] != 0);
      u64 m2 = __ballot(att[rbase + gc * 64 + lane] != 0);
      u64 m3 = __ballot(grp[rbase + gc * 64 + lane] != 0);
      if (lane == 0) {
        size_t ob = ((size_t)(b * 4) * 512 + q) * 8 + gc;
        RB[ob]            = m0;   // c0
        RB[ob + 2 * 4096] = m2;   // c2
        RB[ob + 3 * 4096] = m3;   // c3
      }
    }
  }
}

__global__ void pack_cols_k(const int* __restrict__ att, u64* __restrict__ RB) {
  int t = threadIdx.x, wave = t >> 6, lane = t & 63;
  int b = blockIdx.x >> 3, gc = blockIdx.x & 7;    // 128 blocks
  const int* col = att + ((size_t)(b * 512 + gc * 64 + lane)) * 512;  // att[b][g][.]
#pragma unroll 4
  for (int qi = 0; qi < 128; qi++) {
    int q = wave * 128 + qi;
    u64 m = __ballot(col[q] != 0);
    if (lane == 0) RB[((size_t)(b * 4 + 1) * 512 + q) * 8 + gc] = m;
  }
}

// ---------------------------------------------------------------- pass A: all 12 projections
// C(8192 x 6144) = qb(8192 x 512) * W(512 x 6144). 128x128 tile, BK=64, 4 waves.
__global__ __launch_bounds__(256) void gemm_proj_k(const u16* __restrict__ qb,
                                                   const u16* __restrict__ Wbt,
                                                   u16* __restrict__ P) {
  __shared__ __align__(16) u16 smem[17408];  // As 8192 | Bs 8192; Cs overlays 128x136
  u16* As = smem;
  u16* Bs = smem + 8192;
  int t = threadIdx.x;
  int wave = t >> 6, lane = t & 63, quad = lane >> 4, l16 = lane & 15;
  int m0w = (wave >> 1) * 64, n0w = (wave & 1) * 64;
  int bm = blockIdx.x, bn = blockIdx.y;
  f32x4 acc[4][4] = {};
  int lr8 = lane >> 3;                 // 0..7
  int lc8 = (lane & 7) ^ lr8;         // swizzled logical chunk to fetch
  const u16* ag = qb  + ((size_t)(bm * 128 + wave * 32 + lr8)) * 512 + lc8 * 8;
  const u16* bg = Wbt + ((size_t)(bn * 128 + wave * 32 + lr8)) * 512 + lc8 * 8;
  u16* Asd = As + wave * 2048;        // wave*4 issues * 512 u16
  u16* Bsd = Bs + wave * 2048;
  for (int k0 = 0; k0 < 512; k0 += 64) {
    __syncthreads();                  // prev tile's LDS reads done
#pragma unroll
    for (int j = 0; j < 4; j++) {
      gl_lds16(ag + (size_t)j * 8 * 512 + k0, Asd + j * 512);
      gl_lds16(bg + (size_t)j * 8 * 512 + k0, Bsd + j * 512);
    }
    __syncthreads();                  // vmcnt(0) drain: tiles resident
#pragma unroll
    for (int kc = 0; kc < 2; kc++) {
      bf16x8 am[4], bnf[4];
#pragma unroll
      for (int i = 0; i < 4; i++) {
        int ca = ((kc * 4 + quad) ^ (l16 & 7)) * 8;
        am[i]  = *(const bf16x8*)&As[(m0w + i * 16 + l16) * 64 + ca];
        bnf[i] = *(const bf16x8*)&Bs[(n0w + i * 16 + l16) * 64 + ca];
      }
#pragma unroll
      for (int mt = 0; mt < 4; mt++)
#pragma unroll
        for (int nt = 0; nt < 4; nt++)
          acc[mt][nt] = MFMA16(am[mt], bnf[nt], acc[mt][nt]);
    }
  }
  // ---------------- epilogue: LDS-staged coalesced stores ----------------
  int iw = bn >> 2;                  // both 64-col groups share iw
  bool isV = (iw % 3) == 2;
  int b  = bm >> 2;
  int n0 = (bm & 3) * 128;
  u16 (*Cs)[136] = (u16(*)[136])smem;  // 128 x 136 u16 = 34816 B
  __syncthreads();
#pragma unroll
  for (int mt = 0; mt < 4; mt++)
#pragma unroll
    for (int nt = 0; nt < 4; nt++)
#pragma unroll
      for (int r = 0; r < 4; r++) {
        int rm = m0w + mt * 16 + quad * 4 + r;
        int cn = n0w + nt * 16 + l16;
        u16 v = f2bf(acc[mt][nt][r]);
        if (!isV) Cs[rm][cn] = v;
        else      Cs[cn][rm] = v;
      }
  __syncthreads();
#pragma unroll
  for (int p = 0; p < 8; p++) {
    int idx = p * 256 + t;
    int seg  = idx & 15;
    int crow = idx >> 4;
    uint4 v = *(const uint4*)&Cs[crow][seg * 8];
    if (!isV) {
      int col = seg * 8;
      int cg = col >> 6, k = col & 63;
      int h = (bn * 2 + cg) & 7;
      u16* dst = P + ((size_t)((iw * 8 + h) * 16 + b)) * 32768 + (size_t)(n0 + crow) * 64 + k;
      *(uint4*)dst = v;
    } else {
      int cg = crow >> 6, k = crow & 63;
      int h = (bn * 2 + cg) & 7;
      u16* dst = P + ((size_t)((iw * 8 + h) * 16 + b)) * 32768 + (size_t)k * 512 + n0 + seg * 8;
      *(uint4*)dst = v;
    }
  }
}

// ---------------------------------------------------------------- pass B: fused masked attention
// 1-D grid, 1024 blocks; block 256 = 4 waves, each wave owns 16 q-rows.
// XCD swizzle: all 8 qt-blocks of one (b,h) land on one XCD (id%8 = bh&7) so
// the 512KB K/V panel is L2-resident. Single-buffered K/V, 2 barriers per gt
// (TLP across 5 blocks/CU hides the DMA drain — measured better than in-block
// double-buffering, which cost a block of occupancy). LDS 28.7KB: Ps overlays
// Qs (Q fragments hoisted to regs at gt==0; both are wave-private rows).
// Masks: row-packed u64 bits. Denominator: MFMA with ones-B. Q pre-scaled ->
// bare exp2f.
__global__ __launch_bounds__(256) void attn_k(const u16* __restrict__ P,
                                              const u64* __restrict__ RB,
                                              u16* __restrict__ heads) {
  __shared__ __align__(16) u16 QPs[4096];    // [64][64]: Q at class start, then P scratch
  __shared__ __align__(16) u16 Ks[4096];     // [64][64] swizzled
  __shared__ __align__(16) u16 Vs[4096];     // [v][g] swizzled
  __shared__ __align__(16) u64 Ms[64][8];    // current-class row bitmasks
  int t = threadIdx.x;
  int wave = t >> 6, lane = t & 63, quad = lane >> 4, l16 = lane & 15;
  // id = 8*((bh>>3)*8 + qt) + (bh&7)  — bijective; id%8 keyed to bh
  int id = blockIdx.x;
  int r8 = id & 7, kk = id >> 3;
  int bh = ((kk >> 3) << 3) | r8;
  int qt = kk & 7;
  int b = bh & 15, h = bh >> 4;
  int q0 = qt * 64;
  int lr8 = lane >> 3, lc8 = (lane & 7) ^ lr8;
  int shA = 31 - l16, shB = 15 - l16;
  f32x4 O[4] = {};
  f32x4 Oden = {};
  u16x8 ov = {0x3F80, 0x3F80, 0x3F80, 0x3F80, 0x3F80, 0x3F80, 0x3F80, 0x3F80};
  bf16x8 ones = __builtin_bit_cast(bf16x8, ov);   // bf16 1.0 x8

  auto issueKV = [&](int c, int g0) {
    const u16* PK = P + ((size_t)((3 * c + 1) * 8 + h) * 16 + b) * 32768;
    const u16* PV = P + ((size_t)((3 * c + 2) * 8 + h) * 16 + b) * 32768;
#pragma unroll
    for (int j = 0; j < 2; j++) {
      gl_lds16(PK + (size_t)(g0 + wave * 16 + j * 8 + lr8) * 64 + lc8 * 8,
               Ks + wave * 1024 + j * 512);
      gl_lds16(PV + (size_t)(wave * 16 + j * 8 + lr8) * 512 + g0 + lc8 * 8,
               Vs + wave * 1024 + j * 512);
    }
  };
  auto issueQM = [&](int c) {
    const u16* PQ = P + ((size_t)((3 * c) * 8 + h) * 16 + b) * 32768;
#pragma unroll
    for (int j = 0; j < 2; j++)
      gl_lds16(PQ + (size_t)(q0 + wave * 16 + j * 8 + lr8) * 64 + lc8 * 8,
               QPs + wave * 1024 + j * 512);
    // 1KB/wave of row bitmasks: rows q0+wave*16..+15, all 8 g-chunks
    gl_lds16((const char*)RB + ((size_t)((b * 4 + c) * 512 + q0 + wave * 16)) * 64 + lane * 16,
             &Ms[wave * 16][0]);
  };

  issueQM(0);
  issueKV(0, 0);
  bf16x8 aq0, aq1;
  for (int c = 0; c < 4; c++) {
    for (int gt = 0; gt < 8; gt++) {
      __syncthreads();               // DMA drained: K/V (+Q/M at gt==0) resident
      if (gt == 0) {                 // Q fragments are gt-invariant: hoist to regs
        aq0 = *(const bf16x8*)&QPs[(wave * 16 + l16) * 64 + ((quad) ^ (l16 & 7)) * 8];
        aq1 = *(const bf16x8*)&QPs[(wave * 16 + l16) * 64 + ((4 + quad) ^ (l16 & 7)) * 8];
      }
      f32x4 S[4];
#pragma unroll
      for (int nt = 0; nt < 4; nt++) {
        bf16x8 bk0 = *(const bf16x8*)&Ks[(nt * 16 + l16) * 64 + ((quad) ^ (l16 & 7)) * 8];
        bf16x8 bk1 = *(const bf16x8*)&Ks[(nt * 16 + l16) * 64 + ((4 + quad) ^ (l16 & 7)) * 8];
        f32x4 sa = {};
        sa = MFMA16(aq0, bk0, sa);
        sa = MFMA16(aq1, bk1, sa);
        S[nt] = sa;
      }
      // softmax numerators -> Ps (overlays QPs; wave-private rows, aq already
      // in regs and the QK MFMAs above force the lgkm wait before these writes)
#pragma unroll
      for (int r = 0; r < 4; r++) {
        u64 m = Ms[wave * 16 + quad * 4 + r][gt];       // broadcast b64, conflict-free
        u32 mlo = (u32)m, mhi = (u32)(m >> 32);
        int prow = wave * 16 + quad * 4 + r;
        int rx = prow & 7;
#pragma unroll
        for (int nt = 0; nt < 4; nt++) {
          float e = exp2f(S[nt][r]);                    // W_Q pre-scaled by 0.125*log2e
          u32 w2 = (nt & 2) ? mhi : mlo;
          int sh = (nt & 1) ? shB : shA;
          u32 msk = (u32)((int)(w2 << sh) >> 31);       // bit -> all-ones/zero
          u32 em = __builtin_bit_cast(u32, e) & msk;
          int pcol = (((nt * 2 + (l16 >> 3)) ^ rx) * 8) + (l16 & 7);
          QPs[prow * 64 + pcol] = (u16)((em + 0x8000u) >> 16);
        }
      }
#pragma unroll
      for (int kc = 0; kc < 2; kc++) {
        bf16x8 ap = *(const bf16x8*)&QPs[(wave * 16 + l16) * 64 + (((kc * 4 + quad) ^ (l16 & 7)) * 8)];
#pragma unroll
        for (int vt = 0; vt < 4; vt++) {
          bf16x8 bv = *(const bf16x8*)&Vs[(vt * 16 + l16) * 64 + (((kc * 4 + quad) ^ (l16 & 7)) * 8)];
          O[vt] = MFMA16(ap, bv, O[vt]);
        }
        Oden = MFMA16(ap, ones, Oden);                  // row-sum of P = denominator
      }
      __syncthreads();               // all LDS reads of this gt done
      if (gt < 7)      issueKV(c, (gt + 1) * 64);
      else if (c < 3) { issueQM(c + 1); issueKV(c + 1, 0); }
    }
  }
#pragma unroll
  for (int r = 0; r < 4; r++) {
    float den = Oden[r];             // every lane holds its rows' denominator
#pragma unroll
    for (int vt = 0; vt < 4; vt++) {
      float val = (den > 0.f) ? O[vt][r] / den : 0.f;
      heads[((size_t)(h * 16 + b) * 512 + q0 + wave * 16 + quad * 4 + r) * 64 + vt * 16 + l16] =
          f2bf(val);
    }
  }
}

// ---------------------------------------------------------------- pass C: out = heads x W_out
// out(8192 x 512) = heads[(b,q),(h,v)=512] * Wot. 64x64 tile, K-loop over h.
__global__ __launch_bounds__(256) void gemm_out_k(const u16* __restrict__ heads,
                                                  const u16* __restrict__ Wot,
                                                  float* __restrict__ out) {
  __shared__ __align__(16) u16 As[4096];
  __shared__ __align__(16) u16 Bs[4096];
  int t = threadIdx.x;
  int wave = t >> 6, lane = t & 63, quad = lane >> 4, l16 = lane & 15;
  int m0 = blockIdx.x * 64, e0 = blockIdx.y * 64;
  int b = m0 >> 9, q0 = m0 & 511;
  int lr8 = lane >> 3, lc8 = (lane & 7) ^ lr8;
  f32x4 acc[4] = {};
  for (int h = 0; h < 8; h++) {
    __syncthreads();
#pragma unroll
    for (int j = 0; j < 2; j++) {
      gl_lds16(heads + ((size_t)(h * 16 + b) * 512 + q0 + wave * 16 + j * 8 + lr8) * 64 + lc8 * 8,
               As + wave * 1024 + j * 512);
      gl_lds16(Wot + ((size_t)(h * 512 + e0 + wave * 16 + j * 8 + lr8)) * 64 + lc8 * 8,
               Bs + wave * 1024 + j * 512);
    }
    __syncthreads();
#pragma unroll
    for (int kc = 0; kc < 2; kc++) {
      bf16x8 af = *(const bf16x8*)&As[(wave * 16 + l16) * 64 + ((kc * 4 + quad) ^ (l16 & 7)) * 8];
#pragma unroll
      for (int nt = 0; nt < 4; nt++) {
        bf16x8 bfr = *(const bf16x8*)&Bs[(nt * 16 + l16) * 64 + ((kc * 4 + quad) ^ (l16 & 7)) * 8];
        acc[nt] = MFMA16(af, bfr, acc[nt]);
      }
    }
  }
#pragma unroll
  for (int nt = 0; nt < 4; nt++)
#pragma unroll
    for (int r = 0; r < 4; r++)
      out[((size_t)(b * 512 + q0 + wave * 16 + quad * 4 + r)) * 512 + e0 + nt * 16 + l16] = acc[nt][r];
}

// ---------------------------------------------------------------- launch

extern "C" void kernel_launch(void* const* d_in, const int* in_sizes, int n_in,
                              void* d_out, int out_size, void* d_ws, size_t ws_size,
                              hipStream_t stream) {
  const float* q   = (const float*)d_in[0];
  const int*   att = (const int*)d_in[1];
  const int*   grp = (const int*)d_in[2];
  const int*   sd  = (const int*)d_in[3];
  WPtrs wp;
  for (int j = 0; j < 12; j++) wp.w[j] = (const float*)d_in[4 + j];
  const float* wout = (const float*)d_in[16];

  char* ws = (char*)d_ws;
  // workspace layout (total 126,353,408 B)
  u16* qb    = (u16*)(ws + 0);            //   8,388,608
  u16* Wbt   = (u16*)(ws + 8388608);      //   6,291,456
  u16* Wot   = (u16*)(ws + 14680064);     //     524,288
  u64* RB    = (u64*)(ws + 15204352);     //   2,097,152  (bit-packed masks)
  u16* P     = (u16*)(ws + 17301504);     // 100,663,296
  u16* heads = (u16*)(ws + 117964800);    //   8,388,608
  float* out = (float*)d_out;

  pack_rows_k<<<512, 256, 0, stream>>>(att, grp, sd, RB);
  pack_cols_k<<<128, 256, 0, stream>>>(att, RB);
  prep_q_k<<<2048, 256, 0, stream>>>(q, qb);
  prep_w_k<<<96, 256, 0, stream>>>(wp, Wbt);
  prep_wout_k<<<8, 256, 0, stream>>>(wout, Wot);
  gemm_proj_k<<<dim3(64, 48), 256, 0, stream>>>(qb, Wbt, P);
  attn_k<<<1024, 256, 0, stream>>>(P, RB, heads);
  gemm_out_k<<<dim3(128, 8), 256, 0, stream>>>(heads, Wot, out);
}